// Round 10
// baseline (96.564 us; speedup 1.0000x reference)
//
#include <hip/hip_runtime.h>

// StableContrastiveLoss on MI355X (gfx950).  B=4096, D=512, C=10, T=0.07.
// Round 10: 128x128 tiles, fence-free. R9 post-mortem: 64x64 tiling's L2
// staging traffic (266MB, ~7.7us) was the binding sim term; 128x128 halves
// it (135MB). R3 already proved this structure's kernel cost ~7us once its
// __threadfence (~79us across 528 blocks) is subtracted. Atomic-free P-store
// epilogue (R8). XOR chunk swizzle: conflict-free (each 8-lane b128 phase
// spans all 8 chunk groups). NEVER per-block __threadfence (R6).
// ws: F_bf16[4096*512] | cls[4096] | P_all[32*32*128] | P_pos[...] | totals[2]

#define B_ROWS 4096
#define D_DIM  512
#define C_CLS  10
#define NTB    32                      // 4096/128 tile-blocks per dim
#define NTILES (NTB * (NTB + 1) / 2)   // 528 upper-triangle tiles

typedef __bf16 bf16x8 __attribute__((ext_vector_type(8)));
typedef float  f32x4  __attribute__((ext_vector_type(4)));

// async global->LDS DMA, 16B/lane; LDS dest = wave-uniform base + lane*16
__device__ __forceinline__ void load_lds16(const __bf16* g, __bf16* l) {
  __builtin_amdgcn_global_load_lds(
      (const __attribute__((address_space(1))) unsigned int*)g,
      (__attribute__((address_space(3))) unsigned int*)l, 16, 0, 0);
}

// ---------------- Kernel 1: normalize rows + class extract ----------------
__global__ __launch_bounds__(256) void prep_kernel(
    const float* __restrict__ feats, const float* __restrict__ labels,
    __bf16* __restrict__ F, int* __restrict__ cls,
    float* __restrict__ totals) {
  const int w = threadIdx.x >> 6, lane = threadIdx.x & 63;
  const int row = blockIdx.x * 4 + w;   // one wave per row
  const float* fr = feats + (size_t)row * D_DIM;
  float4 v0 = ((const float4*)fr)[2 * lane];
  float4 v1 = ((const float4*)fr)[2 * lane + 1];
  float ss = v0.x*v0.x + v0.y*v0.y + v0.z*v0.z + v0.w*v0.w
           + v1.x*v1.x + v1.y*v1.y + v1.z*v1.z + v1.w*v1.w;
  #pragma unroll
  for (int m = 1; m < 64; m <<= 1) ss += __shfl_xor(ss, m, 64);
  float inv = 1.0f / sqrtf(ss);

  bf16x8 o;
  o[0] = (__bf16)(v0.x * inv); o[1] = (__bf16)(v0.y * inv);
  o[2] = (__bf16)(v0.z * inv); o[3] = (__bf16)(v0.w * inv);
  o[4] = (__bf16)(v1.x * inv); o[5] = (__bf16)(v1.y * inv);
  o[6] = (__bf16)(v1.z * inv); o[7] = (__bf16)(v1.w * inv);
  *(bf16x8*)(F + (size_t)row * D_DIM + 8 * lane) = o;

  float lv = (lane < C_CLS) ? labels[(size_t)row * C_CLS + lane] : 0.f;
  unsigned long long m = __ballot(lv > 0.5f);
  if (lane == 0) cls[row] = (int)(__ffsll((long long)m) - 1);
  if (blockIdx.x == 0 && threadIdx.x == 0) { totals[0] = 0.f; totals[1] = 0.f; }
}

// ------ Kernel 2: symmetric 128x128-tile sim, DMA staging, no atomics ------
// 4 waves in a 2x2 grid: wave (wi,wj) computes rows 64wi..+63 x cols 64wj..+63
// via acc[4][4]. LDS[row][c] = global chunk c^(row&7). Partials stored
// exactly once: tile(bi,bj) -> P[bi][bj][*] rows; P[bj][bi][*] cols (offdiag).
__global__ __launch_bounds__(256) void sim_kernel(
    const __bf16* __restrict__ F, const int* __restrict__ cls,
    float* __restrict__ P_all, float* __restrict__ P_pos) {
  __shared__ __align__(16) __bf16 Abuf[128 * 64];
  __shared__ __align__(16) __bf16 Bbuf[128 * 64];
  __shared__ int clsA[128], clsB[128];
  __shared__ float g_row_all[128], g_row_pos[128];
  __shared__ float g_col_all[128], g_col_pos[128];

  // triangular tile decode (block-uniform scalar loop, <=32 iters)
  int rem = blockIdx.x, bi = 0, rowlen = NTB;
  while (rem >= rowlen) { rem -= rowlen; ++bi; --rowlen; }
  const int bj = bi + rem;
  const int i0 = bi * 128, j0 = bj * 128;
  const bool offdiag = (bi != bj);

  const int t = threadIdx.x;       // 256 threads = 4 waves
  const int w = t >> 6, lane = t & 63;
  const int wi = w & 1, wj = w >> 1;   // 2x2 wave grid
  const int q = lane >> 4, cl = lane & 15;

  if (t < 128) { clsA[t] = cls[i0 + t]; g_row_all[t] = 0.f; g_row_pos[t] = 0.f; }
  else { clsB[t-128] = cls[j0 + t - 128]; g_col_all[t-128] = 0.f; g_col_pos[t-128] = 0.f; }

  f32x4 acc[4][4];
  #pragma unroll
  for (int ri = 0; ri < 4; ++ri)
    #pragma unroll
    for (int cj = 0; cj < 4; ++cj) acc[ri][cj] = (f32x4){0.f, 0.f, 0.f, 0.f};

  // DMA roles: lane L -> subrow L/8, LDS chunk L%8, global chunk (L%8)^(L/8)
  const int srow = lane >> 3;
  const int sg   = (lane & 7) ^ srow;

  for (int k0 = 0; k0 < D_DIM; k0 += 64) {
    __syncthreads();  // previous readers done (also covers cls/g_* init)
    #pragma unroll
    for (int r = 0; r < 4; ++r) {
      const int rowbase = w * 32 + r * 8;   // wave-uniform, multiple of 8
      load_lds16(F + (size_t)(i0 + rowbase + srow) * D_DIM + k0 + sg * 8,
                 &Abuf[rowbase * 64]);
      load_lds16(F + (size_t)(j0 + rowbase + srow) * D_DIM + k0 + sg * 8,
                 &Bbuf[rowbase * 64]);
    }
    __syncthreads();  // barrier drain completes the DMA

    #pragma unroll
    for (int kk = 0; kk < 64; kk += 32) {
      const int cc = ((kk >> 3) + q) ^ (cl & 7);   // swizzled LDS chunk
      bf16x8 af[4], bfr[4];
      #pragma unroll
      for (int ri = 0; ri < 4; ++ri)
        af[ri] = *(const bf16x8*)&Abuf[(64 * wi + 16 * ri + cl) * 64 + cc * 8];
      #pragma unroll
      for (int cj = 0; cj < 4; ++cj)
        bfr[cj] = *(const bf16x8*)&Bbuf[(64 * wj + 16 * cj + cl) * 64 + cc * 8];
      #pragma unroll
      for (int ri = 0; ri < 4; ++ri)
        #pragma unroll
        for (int cj = 0; cj < 4; ++cj)
          acc[ri][cj] = __builtin_amdgcn_mfma_f32_16x16x32_bf16(
              af[ri], bfr[cj], acc[ri][cj], 0, 0, 0);
    }
  }

  // Epilogue. D layout (m89/m91): col = lane&15, row = (lane>>4)*4 + reg.
  const float invT = 1.0f / 0.07f;
  float cs_all[4] = {0.f, 0.f, 0.f, 0.f};
  float cs_pos[4] = {0.f, 0.f, 0.f, 0.f};

  #pragma unroll
  for (int ri = 0; ri < 4; ++ri) {
    float ra[4] = {0.f, 0.f, 0.f, 0.f};
    float rp[4] = {0.f, 0.f, 0.f, 0.f};
    #pragma unroll
    for (int cj = 0; cj < 4; ++cj) {
      const int jloc = 64 * wj + 16 * cj + cl;
      const int gj = j0 + jloc;
      const int cjc = clsB[jloc];
      #pragma unroll
      for (int r = 0; r < 4; ++r) {
        const int iloc = 64 * wi + 16 * ri + q * 4 + r;
        const int gi = i0 + iloc;
        float s = acc[ri][cj][r] * invT;
        s = fminf(fmaxf(s, -20.f), 20.f);
        const bool diag = (gi == gj);
        float e = diag ? 0.f : __expf(s);
        ra[r] += e;
        cs_all[cj] += e;
        if (!diag && cjc == clsA[iloc]) { rp[r] += e; cs_pos[cj] += e; }
      }
    }
    // row partials (this wave's 64 cols) -> LDS atomic combine of 2 wj-waves
    #pragma unroll
    for (int r = 0; r < 4; ++r) {
      float sa = ra[r], sp = rp[r];
      #pragma unroll
      for (int m = 1; m < 16; m <<= 1) {
        sa += __shfl_xor(sa, m, 64);
        sp += __shfl_xor(sp, m, 64);
      }
      if (cl == 0) {
        const int rloc = 64 * wi + 16 * ri + q * 4 + r;
        atomicAdd(&g_row_all[rloc], sa);   // LDS-scope, cheap
        atomicAdd(&g_row_pos[rloc], sp);
      }
    }
  }
  // col partials (this wave's 64 rows) -> LDS atomic combine of 2 wi-waves
  if (offdiag) {
    #pragma unroll
    for (int cj = 0; cj < 4; ++cj) {
      float sa = cs_all[cj], sp = cs_pos[cj];
      sa += __shfl_xor(sa, 16, 64); sa += __shfl_xor(sa, 32, 64);
      sp += __shfl_xor(sp, 16, 64); sp += __shfl_xor(sp, 32, 64);
      if (q == 0) {
        const int jloc = 64 * wj + 16 * cj + cl;
        atomicAdd(&g_col_all[jloc], sa);
        atomicAdd(&g_col_pos[jloc], sp);
      }
    }
  }
  __syncthreads();

  // store phase: coalesced 512B stores, exactly-once slot coverage
  if (t < 128) {
    const size_t base_row = ((size_t)bi * NTB + bj) * 128;
    P_all[base_row + t] = g_row_all[t];
    P_pos[base_row + t] = g_row_pos[t];
  } else if (offdiag) {
    const size_t base_col = ((size_t)bj * NTB + bi) * 128;
    P_all[base_col + t - 128] = g_col_all[t - 128];
    P_pos[base_col + t - 128] = g_col_pos[t - 128];
  }
}

// ---- Kernel 3: per-strip reduction (32 blocks), tiny atomics to totals ----
__global__ __launch_bounds__(256) void finalize_kernel(
    const float* __restrict__ P_all, const float* __restrict__ P_pos,
    float* __restrict__ totals) {
  __shared__ float Sall[4096], Spos[4096];   // 32 slots x 128 rows
  __shared__ float redL[2], redC[2];
  const int s = blockIdx.x;
  const int t = threadIdx.x;
  for (int i = t; i < 4096; i += 256) {
    Sall[i] = P_all[(size_t)s * 4096 + i];   // coalesced
    Spos[i] = P_pos[(size_t)s * 4096 + i];
  }
  __syncthreads();
  if (t < 128) {   // waves 0,1: row r = t of this 128-row strip
    float a = 0.f, p = 0.f;
    #pragma unroll 8
    for (int k = 0; k < 32; ++k) {   // stride-128: 2-way bank alias (free)
      a += Sall[k * 128 + t];
      p += Spos[k * 128 + t];
    }
    float loss = 0.f, cnt = 0.f;
    if (p > 0.f) {                   // valid iff >=1 positive
      loss = -logf(p / (a + 1e-8f) + 1e-8f);
      cnt = 1.f;
    }
    #pragma unroll
    for (int m = 1; m < 64; m <<= 1) {
      loss += __shfl_xor(loss, m, 64);
      cnt  += __shfl_xor(cnt, m, 64);
    }
    if ((t & 63) == 0) { redL[t >> 6] = loss; redC[t >> 6] = cnt; }
  }
  __syncthreads();
  if (t == 0) {                      // 64 atomics total across the grid
    atomicAdd(&totals[0], redL[0] + redL[1]);
    atomicAdd(&totals[1], redC[0] + redC[1]);
  }
}

// ---------------- Kernel 4: scalar division ----------------
__global__ void div_kernel(const float* __restrict__ totals,
                           float* __restrict__ out) {
  out[0] = (totals[1] > 0.f) ? (totals[0] / totals[1]) : 0.f;
}

extern "C" void kernel_launch(void* const* d_in, const int* in_sizes, int n_in,
                              void* d_out, int out_size, void* d_ws, size_t ws_size,
                              hipStream_t stream) {
  const float* features = (const float*)d_in[0];
  const float* labels   = (const float*)d_in[1];
  float* out = (float*)d_out;

  __bf16* F      = (__bf16*)d_ws;
  int*    cls    = (int*)((char*)d_ws + (size_t)B_ROWS * D_DIM * 2);
  float*  P_all  = (float*)((char*)cls + B_ROWS * sizeof(int));
  float*  P_pos  = P_all + (size_t)NTB * NTB * 128;
  float*  totals = P_pos + (size_t)NTB * NTB * 128;

  prep_kernel<<<B_ROWS / 4, 256, 0, stream>>>(features, labels, F, cls, totals);
  sim_kernel<<<NTILES, 256, 0, stream>>>(F, cls, P_all, P_pos);
  finalize_kernel<<<NTB, 256, 0, stream>>>(P_all, P_pos, totals);
  div_kernel<<<1, 1, 0, stream>>>(totals, out);
}